// Round 3
// baseline (315.016 us; speedup 1.0000x reference)
//
#include <hip/hip_runtime.h>

typedef _Float16 half_t;
typedef _Float16 half4 __attribute__((ext_vector_type(4)));
typedef _Float16 half8 __attribute__((ext_vector_type(8)));
typedef float floatx4 __attribute__((ext_vector_type(4)));

#define B_ 32
#define T_ 512
#define H_ 256
#define L_ 2048

// ------------------------------------------------------------------
// Fused setup: blocks [0,128) = meta, blocks [128,512) = weight prep.
// NEW Wp layout, phase-major for LDS staging:
//   chunk c = ((pred*4+layer)*2 + (nt>>3))*64 + kk*8 + (nt&7)
//   within chunk: lane l holds 8 halves W[kk*32+(l>>4)*8+j][nt*16+(l&15)]
// A phase (pred,layer,nh) = 64 contiguous chunks = 64 KB.
// ------------------------------------------------------------------
__global__ __launch_bounds__(256) void setup_kernel(
    const int* __restrict__ dur,
    const float* __restrict__ pitch_t,
    const float* __restrict__ energy_t,
    const float* __restrict__ dur_W,
    const float* __restrict__ pit_W,
    const float* __restrict__ en_W,
    half_t* __restrict__ Wp,
    int* __restrict__ idx_ws,
    int* __restrict__ pi_ws,
    int* __restrict__ ei_ws,
    int* __restrict__ ml_ws,
    float* __restrict__ out4,
    float* __restrict__ out5) {
  __shared__ int cum_l[T_];
  __shared__ int ml_s;
  int bid = blockIdx.x;
  int tid = threadIdx.x;

  if (bid >= 128) {
    int g = (bid - 128) * 256 + tid;          // [0, 98304)
    int lane = g & 63;
    int t = g >> 6;                            // [0, 1536)
    int nt = t & 15;
    int kk = (t >> 4) & 7;
    int layer = (t >> 7) & 3;
    int pred = t >> 9;
    const float* W = (pred == 0 ? dur_W : (pred == 1 ? pit_W : en_W)) + layer * 65536;
    int n = nt * 16 + (lane & 15);
    int k0 = kk * 32 + (lane >> 4) * 8;
    half8 o;
#pragma unroll
    for (int j = 0; j < 8; ++j) o[j] = (half_t)W[(k0 + j) * 256 + n];
    int c = ((pred * 4 + layer) * 2 + (nt >> 3)) * 64 + kk * 8 + (nt & 7);
    *(half8*)&Wp[(size_t)c * 512 + lane * 8] = o;
    return;
  }

  int b = bid >> 2;
  int chunk = bid & 3;
  if (tid < 64) {
    int l = tid;
    const int* dr = dur + b * T_;
    int v[8];
    int base = l * 8;
#pragma unroll
    for (int j = 0; j < 8; ++j) v[j] = dr[base + j];
#pragma unroll
    for (int j = 1; j < 8; ++j) v[j] += v[j - 1];
    int tot = v[7];
    int inc = tot;
    for (int d = 1; d < 64; d <<= 1) {
      int t = __shfl_up(inc, d);
      if (l >= d) inc += t;
    }
    int excl = inc - tot;
#pragma unroll
    for (int j = 0; j < 8; ++j) cum_l[base + j] = excl + v[j];
    if (l == 63) {
      int mel = min(inc, L_);
      ml_s = mel;
      if (chunk == 0) {
        ml_ws[b] = mel;
        out4[b] = (float)mel;
      }
    }
  }
  __syncthreads();
  int ml = ml_s;
#pragma unroll
  for (int j = 0; j < 2; ++j) {
    int m = chunk * 512 + j * 256 + tid;
    int lo = 0;
#pragma unroll
    for (int sh = 8; sh >= 0; --sh) {
      int c = lo + (1 << sh);
      if (c <= T_ && cum_l[c - 1] <= m) lo = c;
    }
    int idx = min(lo, T_ - 1);
    int g = b * L_ + m;
    idx_ws[g] = idx;
    pi_ws[g] = (int)ceilf(pitch_t[g] * 256.0f);
    ei_ws[g] = (int)ceilf(energy_t[g] * 256.0f);
    out5[g] = (m >= ml) ? 1.0f : 0.0f;
  }
}

// ------------------------------------------------------------------
// Predictor: 576 blocks x 512 threads (8 waves).
// blocks [0,256): pitch  [256,512): energy  [512,576): duration.
// 256 rows/block, wave w owns rows w*32..w*32+31; h lives in REGISTERS
// (hf[2][8] half8 = 64 VGPR per wave). Weights double-buffered through
// LDS (2 x 64 KB), phase = half-layer (8 nt-tiles x all 8 kk), shared
// by all 8 waves -> weight L2 traffic /8 vs per-wave streaming.
// Per phase per wave: 128 MFMA (~1240 cyc/SIMD) + 8x16B reg-staged
// prefetch of next phase + acc->hf transpose via per-wave LDS bounce.
// One barrier per phase (8 total). acc is phase-local (64 VGPR).
// Head computed from register h directly (shfl reduce).
// ------------------------------------------------------------------
__global__ __launch_bounds__(512, 2) void predictor_kernel(
    const float* __restrict__ x,
    const half_t* __restrict__ Wp,
    const float* __restrict__ dur_b, const float* __restrict__ dur_w, const float* __restrict__ dur_b2,
    const float* __restrict__ pit_b, const float* __restrict__ pit_w, const float* __restrict__ pit_b2,
    const float* __restrict__ en_b,  const float* __restrict__ en_w,  const float* __restrict__ en_b2,
    const int* __restrict__ idx_ws, const int* __restrict__ pi_ws, const int* __restrict__ ei_ws,
    const int* __restrict__ mlw,
    const float* __restrict__ src_seq, const unsigned char* __restrict__ src_mask,
    const float* __restrict__ pemb, const float* __restrict__ eemb,
    float* __restrict__ out0, float* __restrict__ out1,
    float* __restrict__ out2, float* __restrict__ out3) {
  __shared__ half_t wlds[65536];       // two 32768-half (64 KB) weight buffers
  __shared__ half_t bounce[8][640];    // per-wave 16 rows x 40 halves (80 B stride)

  int bid = blockIdx.x;
  int mode, blk, pred;
  const float* bias; const float* wh; const float* b2p; float* outp;
  if (bid < 256)      { mode = 1; blk = bid;       pred = 1; bias = pit_b; wh = pit_w; b2p = pit_b2; outp = out2; }
  else if (bid < 512) { mode = 2; blk = bid - 256; pred = 2; bias = en_b;  wh = en_w;  b2p = en_b2;  outp = out3; }
  else                { mode = 0; blk = bid - 512; pred = 0; bias = dur_b; wh = dur_w; b2p = dur_b2; outp = out1; }

  int tid = threadIdx.x;
  int wv = tid >> 6, lane = tid & 63;
  int mi = lane & 15, qi = lane >> 4;
  int brow0 = blk * 256;
  int wrow0 = brow0 + wv * 32;          // this wave's 32 global rows
  const half_t* Wpp = Wp + (size_t)pred * 262144;

  // ---- initial h staging: gather rows -> f16 -> per-wave LDS slice -> hf regs ----
  half_t* slice = &wlds[wv * 8192];     // 32 rows x 256 halves (16 KB), transient
  if (mode == 0) {
    for (int it = 0; it < 32; ++it) {
      const float4 xv = *(const float4*)&x[(size_t)(wrow0 + it) * H_ + lane * 4];
      half4 h4;
      h4[0] = (half_t)xv.x; h4[1] = (half_t)xv.y;
      h4[2] = (half_t)xv.z; h4[3] = (half_t)xv.w;
      *(half4*)&slice[it * 256 + lane * 4] = h4;
    }
  } else {
    int b = brow0 >> 11;                // 256-row block lies within one batch
    int ml = mlw[b];
    int m0 = (brow0 & (L_ - 1)) + wv * 32;
    for (int it = 0; it < 32; ++it) {
      int m = m0 + it;
      int g = wrow0 + it;               // == b*L_ + m
      float4 xv = {0.f, 0.f, 0.f, 0.f};
      if (m < ml) {
        int ir = idx_ws[g];
        xv = *(const float4*)&x[((size_t)(b * T_ + ir)) * H_ + lane * 4];
      }
      if (mode == 1) {
        const float4 pv = *(const float4*)&pemb[(size_t)pi_ws[g] * H_ + lane * 4];
        const float4 ev = *(const float4*)&eemb[(size_t)ei_ws[g] * H_ + lane * 4];
        floatx4 o;
        o[0] = xv.x + pv.x + ev.x;
        o[1] = xv.y + pv.y + ev.y;
        o[2] = xv.z + pv.z + ev.z;
        o[3] = xv.w + pv.w + ev.w;
        __builtin_nontemporal_store(o, (floatx4*)&out0[(size_t)g * H_ + lane * 4]);
      }
      half4 h4;
      h4[0] = (half_t)xv.x; h4[1] = (half_t)xv.y;
      h4[2] = (half_t)xv.z; h4[3] = (half_t)xv.w;
      *(half4*)&slice[it * 256 + lane * 4] = h4;
    }
  }
  half8 hf[2][8];                       // h[mt*16+mi][kk*32+qi*8 ..+7]
#pragma unroll
  for (int mt = 0; mt < 2; ++mt)
#pragma unroll
    for (int kk = 0; kk < 8; ++kk)
      hf[mt][kk] = *(const half8*)&slice[(mt * 16 + mi) * 256 + kk * 32 + qi * 8];
  __syncthreads();                      // bounce reads done before staging overwrites

  // ---- prologue: stage phase 0 (layer 0, nh 0) into buf0 ----
  {
    float4 s0[8];
#pragma unroll
    for (int i = 0; i < 8; ++i)
      s0[i] = *(const float4*)&Wpp[wv * 4096 + i * 512 + lane * 8];
#pragma unroll
    for (int i = 0; i < 8; ++i)
      *(float4*)&wlds[wv * 4096 + i * 512 + lane * 8] = s0[i];
  }
  __syncthreads();

  half8 hfn[2][8];

  // Phase NH: compute from buf[NH]; reg-stage next phase -> buf[NH^1];
  // tail: acc + bias -> relu -> f16 -> bounce transpose -> hfn[.][NH*4+kp].
#define PHASE(NH, DO_STAGE)                                                        \
  {                                                                                \
    const half_t* bufC = &wlds[(NH) * 32768];                                      \
    float4 stg[8];                                                                 \
    if (DO_STAGE) {                                                                \
      const half_t* srcp = Wpp + (size_t)(layer * 2 + (NH) + 1) * 32768;           \
      _Pragma("unroll")                                                            \
      for (int i = 0; i < 8; ++i)                                                  \
        stg[i] = *(const float4*)&srcp[wv * 4096 + i * 512 + lane * 8];            \
    }                                                                              \
    floatx4 acc[8][2];                                                             \
    _Pragma("unroll")                                                              \
    for (int u = 0; u < 8; ++u) {                                                  \
      acc[u][0] = (floatx4){0.f, 0.f, 0.f, 0.f};                                   \
      acc[u][1] = (floatx4){0.f, 0.f, 0.f, 0.f};                                   \
    }                                                                              \
    _Pragma("unroll")                                                              \
    for (int np = 0; np < 4; ++np) {                                               \
      _Pragma("unroll")                                                            \
      for (int kk = 0; kk < 8; ++kk) {                                             \
        half8 w0 = *(const half8*)&bufC[(kk * 8 + 2 * np) * 512 + lane * 8];       \
        half8 w1 = *(const half8*)&bufC[(kk * 8 + 2 * np + 1) * 512 + lane * 8];   \
        acc[2 * np][0]     = __builtin_amdgcn_mfma_f32_16x16x32_f16(w0, hf[0][kk], acc[2 * np][0], 0, 0, 0);     \
        acc[2 * np][1]     = __builtin_amdgcn_mfma_f32_16x16x32_f16(w0, hf[1][kk], acc[2 * np][1], 0, 0, 0);     \
        acc[2 * np + 1][0] = __builtin_amdgcn_mfma_f32_16x16x32_f16(w1, hf[0][kk], acc[2 * np + 1][0], 0, 0, 0); \
        acc[2 * np + 1][1] = __builtin_amdgcn_mfma_f32_16x16x32_f16(w1, hf[1][kk], acc[2 * np + 1][1], 0, 0, 0); \
      }                                                                            \
    }                                                                              \
    if (DO_STAGE) {                                                                \
      half_t* dstp = &wlds[((NH) ^ 1) * 32768];                                    \
      _Pragma("unroll")                                                            \
      for (int i = 0; i < 8; ++i)                                                  \
        *(float4*)&dstp[wv * 4096 + i * 512 + lane * 8] = stg[i];                  \
    }                                                                              \
    const float* bl = bias + layer * 256 + (NH) * 128;                             \
    _Pragma("unroll")                                                              \
    for (int mt = 0; mt < 2; ++mt) {                                               \
      _Pragma("unroll")                                                            \
      for (int kp = 0; kp < 4; ++kp) {                                             \
        _Pragma("unroll")                                                          \
        for (int hh = 0; hh < 2; ++hh) {                                           \
          int ntl = kp * 2 + hh;                                                   \
          float4 bv = *(const float4*)&bl[ntl * 16 + qi * 4];                      \
          floatx4 a = acc[ntl][mt];                                                \
          half4 h4;                                                                \
          h4[0] = (half_t)fmaxf(a[0] + bv.x, 0.f);                                 \
          h4[1] = (half_t)fmaxf(a[1] + bv.y, 0.f);                                 \
          h4[2] = (half_t)fmaxf(a[2] + bv.z, 0.f);                                 \
          h4[3] = (half_t)fmaxf(a[3] + bv.w, 0.f);                                 \
          *(half4*)&bounce[wv][mi * 40 + hh * 16 + qi * 4] = h4;                   \
        }                                                                          \
        hfn[mt][(NH) * 4 + kp] = *(const half8*)&bounce[wv][mi * 40 + qi * 8];     \
      }                                                                            \
    }                                                                              \
    __syncthreads();                                                               \
  }

#pragma unroll 1
  for (int layer = 0; layer < 4; ++layer) {
    PHASE(0, true);
    PHASE(1, (layer < 3));
#pragma unroll
    for (int mt = 0; mt < 2; ++mt)
#pragma unroll
      for (int kk = 0; kk < 8; ++kk)
        hf[mt][kk] = hfn[mt][kk];
  }

  // ---- head from register h: out = h . w + b2, shfl-reduce over qi ----
#pragma unroll
  for (int mt = 0; mt < 2; ++mt) {
    float sum = 0.f;
#pragma unroll
    for (int kk = 0; kk < 8; ++kk) {
      float4 wa = *(const float4*)&wh[kk * 32 + qi * 8];
      float4 wb = *(const float4*)&wh[kk * 32 + qi * 8 + 4];
      half8 hv = hf[mt][kk];
      sum += (float)hv[0] * wa.x + (float)hv[1] * wa.y + (float)hv[2] * wa.z + (float)hv[3] * wa.w
           + (float)hv[4] * wb.x + (float)hv[5] * wb.y + (float)hv[6] * wb.z + (float)hv[7] * wb.w;
    }
    sum += __shfl_xor(sum, 16);
    sum += __shfl_xor(sum, 32);
    if (qi == 0) {
      int row = wrow0 + mt * 16 + mi;
      float d = sum + b2p[0];
      if (mode == 0) {
        if (src_mask[row]) d = 0.f;
        float s2 = src_seq[(size_t)row * 3 + 2];
        outp[row] = (tanhf(d) + 1.0f) * s2;
      } else {
        int b = row >> 11;
        int m = row & (L_ - 1);
        float v = (m >= mlw[b]) ? 0.f : d;
        outp[row] = (mode == 1) ? fmaxf(v, 0.f) : v;
      }
    }
  }
}

extern "C" void kernel_launch(void* const* d_in, const int* in_sizes, int n_in,
                              void* d_out, int out_size, void* d_ws, size_t ws_size,
                              hipStream_t stream) {
  const float* x        = (const float*)d_in[0];
  const float* src_seq  = (const float*)d_in[1];
  const int*   durt     = (const int*)d_in[2];
  const float* pitcht   = (const float*)d_in[3];
  const float* energyt  = (const float*)d_in[4];
  const unsigned char* src_mask = (const unsigned char*)d_in[5];
  const float* dur_W  = (const float*)d_in[7];
  const float* dur_b  = (const float*)d_in[8];
  const float* dur_w  = (const float*)d_in[9];
  const float* dur_b2 = (const float*)d_in[10];
  const float* pit_W  = (const float*)d_in[11];
  const float* pit_b  = (const float*)d_in[12];
  const float* pit_w  = (const float*)d_in[13];
  const float* pit_b2 = (const float*)d_in[14];
  const float* en_W   = (const float*)d_in[15];
  const float* en_b   = (const float*)d_in[16];
  const float* en_w   = (const float*)d_in[17];
  const float* en_b2  = (const float*)d_in[18];
  const float* pemb   = (const float*)d_in[19];
  const float* eemb   = (const float*)d_in[20];

  float* out0 = (float*)d_out;              // [32,2048,256]
  float* out1 = out0 + 16777216;            // [32,512]   log_duration
  float* out2 = out1 + 16384;               // [32,2048]  pitch_prediction
  float* out3 = out2 + 65536;               // [32,2048]  energy_prediction
  float* out4 = out3 + 65536;               // [32]       mel_len (as float)
  float* out5 = out4 + 32;                  // [32,2048]  mel_mask (0/1 float)

  int* idx_ws = (int*)d_ws;                 // 65536 ints
  int* pi_ws  = idx_ws + 65536;             // 65536 ints
  int* ei_ws  = pi_ws + 65536;              // 65536 ints
  int* ml_ws  = ei_ws + 65536;              // 32 ints
  half_t* Wp  = (half_t*)((char*)d_ws + 786560);  // 786432 halves, 16B aligned

  setup_kernel<<<dim3(512), dim3(256), 0, stream>>>(
      durt, pitcht, energyt, dur_W, pit_W, en_W, Wp,
      idx_ws, pi_ws, ei_ws, ml_ws, out4, out5);
  predictor_kernel<<<dim3(576), dim3(512), 0, stream>>>(
      x, Wp,
      dur_b, dur_w, dur_b2,
      pit_b, pit_w, pit_b2,
      en_b, en_w, en_b2,
      idx_ws, pi_ws, ei_ws, ml_ws, src_seq, src_mask, pemb, eemb,
      out0, out1, out2, out3);
}